// Round 4
// baseline (58.225 us; speedup 1.0000x reference)
//
#include <hip/hip_runtime.h>

// SmoothnessLoss: mean over [B,4,H,W] of smooth_l1(stencil(in - tgt)) * mask
// B=16, C=1, H=W=1024, fp32 in/out. Output: single fp32 scalar.
//
// Stencils on d = in - tgt (conv linear => grads(in)-grads(tgt) = grads(d)):
//   fx  = d(y,x-1) - 2 d(y,x) + d(y,x+1)        mask: zero at x==W-1
//   fy  = d(y-1,x) - 2 d(y,x) + d(y+1,x)        mask: zero at y==H-1
//   fd1 = d(y-1,x-1) - 2 d(y,x) + d(y+1,x+1)    mask: zero on all borders
//   fd2 = d(y-1,x+1) - 2 d(y,x) + d(y+1,x-1)    mask: zero on all borders
//
// R4: latency x MLP bound (R3: VGPR=60 proves compiler sank subs into the
// load loop -> ~2 loads in flight; 27KB/CU in flight / 700cy = the measured
// 3.9 TB/s). Fix: stage rows via global_load_lds (async DMA, no VGPR dep the
// compiler can serialize on). 80KB LDS/block, 2 blocks/CU, 160KB in flight.

#define BB 16
#define HH 1024
#define WW 1024
#define RR 8   // rows per block-strip; load volume = (RR+2)/RR x ideal

typedef __attribute__((address_space(1))) const void GVoid;
typedef __attribute__((address_space(3))) void LVoid;

__device__ __forceinline__ float sl1(float v) {
  float ad = fabsf(v);
  float t = fminf(ad, 1.0f);
  return fmaf(0.5f * t, t, ad - t);   // ad<1 ? 0.5 ad^2 : ad-0.5
}

__global__ __launch_bounds__(256) void smooth_partial(
    const float* __restrict__ in, const float* __restrict__ tg,
    float* __restrict__ ws) {
  __shared__ __align__(16) float As[RR + 2][WW];   // 40 KB: input rows
  __shared__ __align__(16) float Bs[RR + 2][WW];   // 40 KB: target rows
  __shared__ float shred[4];

  const int tid  = threadIdx.x;
  const int lane = tid & 63;
  const int wave = tid >> 6;
  const int x0   = tid * 4;                 // 256 threads x 4 cols = W
  const int strip = blockIdx.x;             // 0 .. B*(H/RR)-1
  const int bi = strip >> 7;                // / (HH/RR) = /128
  const int r0 = (strip & 127) * RR;
  const size_t imgBase = (size_t)bi * HH * WW;

  // ---- stage rows r0-1 .. r0+RR into LDS via async DMA (no VGPR round-trip)
  #pragma unroll
  for (int k = 0; k < RR + 2; ++k) {
    const int y = r0 - 1 + k;
    if (y >= 0 && y < HH) {                 // wave-uniform branch
      const float* ga = in + imgBase + (size_t)y * WW + x0;  // per-lane src
      const float* gb = tg + imgBase + (size_t)y * WW + x0;
      // LDS dest: wave-uniform base, HW adds lane*16
      __builtin_amdgcn_global_load_lds((GVoid*)ga, (LVoid*)&As[k][wave * 256], 16, 0, 0);
      __builtin_amdgcn_global_load_lds((GVoid*)gb, (LVoid*)&Bs[k][wave * 256], 16, 0, 0);
    } else {
      const float4 z = make_float4(0.f, 0.f, 0.f, 0.f);
      *reinterpret_cast<float4*>(&As[k][x0]) = z;
      *reinterpret_cast<float4*>(&Bs[k][x0]) = z;
    }
  }
  asm volatile("s_waitcnt vmcnt(0)" ::: "memory");
  __syncthreads();   // all waves' DMAs landed; halo lanes read across waves

  // ---- diff row from LDS: center float4 + halos (shfl; boundary lanes LDS)
  auto loadD = [&](int k, float4& C, float& L, float& R) {
    const float4 a = *reinterpret_cast<const float4*>(&As[k][x0]);
    const float4 b = *reinterpret_cast<const float4*>(&Bs[k][x0]);
    C.x = a.x - b.x; C.y = a.y - b.y; C.z = a.z - b.z; C.w = a.w - b.w;
    L = __shfl_up(C.w, 1, 64);
    R = __shfl_down(C.x, 1, 64);
    if (lane == 0)  L = (tid > 0)   ? As[k][x0 - 1] - Bs[k][x0 - 1] : 0.f;  // x==0 pad
    if (lane == 63) R = (tid < 255) ? As[k][x0 + 4] - Bs[k][x0 + 4] : 0.f;  // x==1023 pad
  };

  float4 Pc, Cc, Nc;
  float  Pl, Pr, Cl, Cr, Nl, Nr;
  loadD(0, Pc, Pl, Pr);
  loadD(1, Cc, Cl, Cr);

  float sum = 0.f;
  #pragma unroll
  for (int k = 0; k < RR; ++k) {
    const int y = r0 + k;
    loadD(k + 2, Nc, Nl, Nr);
    const float my  = (y == HH - 1) ? 0.f : 1.f;
    const float mdy = (y == 0 || y == HH - 1) ? 0.f : 1.f;
    const float P[6] = {Pl, Pc.x, Pc.y, Pc.z, Pc.w, Pr};
    const float C[6] = {Cl, Cc.x, Cc.y, Cc.z, Cc.w, Cr};
    const float N[6] = {Nl, Nc.x, Nc.y, Nc.z, Nc.w, Nr};
    #pragma unroll
    for (int j = 1; j <= 4; ++j) {
      const int x = x0 + j - 1;
      const float c2 = -2.f * C[j];
      const float fx = (C[j-1] + C[j+1]) + c2;
      const float fy = (P[j]   + N[j]  ) + c2;
      const float f1 = (P[j-1] + N[j+1]) + c2;
      const float f2 = (P[j+1] + N[j-1]) + c2;
      const float mx  = (x == WW - 1) ? 0.f : 1.f;
      const float mdx = (x == 0 || x == WW - 1) ? 0.f : 1.f;
      sum += sl1(fx) * mx + sl1(fy) * my + (sl1(f1) + sl1(f2)) * (mdx * mdy);
    }
    Pl = Cl; Pr = Cr; Pc = Cc;
    Cl = Nl; Cr = Nr; Cc = Nc;
  }

  // ---- deterministic block reduction ----
  for (int off = 32; off > 0; off >>= 1) sum += __shfl_down(sum, off, 64);
  if (lane == 0) shred[wave] = sum;
  __syncthreads();
  if (tid == 0) ws[blockIdx.x] = (shred[0] + shred[1]) + (shred[2] + shred[3]);
}

__global__ __launch_bounds__(256) void smooth_final(
    const float* __restrict__ ws, float* __restrict__ out, int n) {
  float s = 0.f;
  for (int i = threadIdx.x; i < n; i += 256) s += ws[i];
  for (int off = 32; off > 0; off >>= 1) s += __shfl_down(s, off, 64);
  __shared__ float sh[4];
  const int wave = threadIdx.x >> 6, lane = threadIdx.x & 63;
  if (lane == 0) sh[wave] = s;
  __syncthreads();
  if (threadIdx.x == 0) {
    const float scale = 1.0f / (float)((long long)BB * 4LL * HH * WW);
    out[0] = ((sh[0] + sh[1]) + (sh[2] + sh[3])) * scale;
  }
}

extern "C" void kernel_launch(void* const* d_in, const int* in_sizes, int n_in,
                              void* d_out, int out_size, void* d_ws, size_t ws_size,
                              hipStream_t stream) {
  const float* in = (const float*)d_in[0];
  const float* tg = (const float*)d_in[1];
  float* out = (float*)d_out;
  float* ws  = (float*)d_ws;   // B*(H/RR)*4 = 8 KiB, well under ws_size

  const int nblocks = BB * (HH / RR);  // 2048 blocks, 256 threads each
  smooth_partial<<<nblocks, 256, 0, stream>>>(in, tg, ws);
  smooth_final<<<1, 256, 0, stream>>>(ws, out, nblocks);
}

// Round 5
// 36.187 us; speedup vs baseline: 1.6090x; 1.6090x over previous
//
#include <hip/hip_runtime.h>

// SmoothnessLoss: mean over [B,4,H,W] of smooth_l1(stencil(in - tgt)) * mask
// B=16, C=1, H=W=1024, fp32 in/out. Output: single fp32 scalar.
//
// Stencils on d = in - tgt (conv linear => grads(in)-grads(tgt) = grads(d)):
//   fx  = d(y,x-1) - 2 d(y,x) + d(y,x+1)        mask: zero at x==W-1
//   fy  = d(y-1,x) - 2 d(y,x) + d(y+1,x)        mask: zero at y==H-1
//   fd1 = d(y-1,x-1) - 2 d(y,x) + d(y+1,x+1)    mask: zero on all borders
//   fd2 = d(y-1,x+1) - 2 d(y,x) + d(y+1,x-1)    mask: zero on all borders
//
// R5: latency x MLP bound. R2/R3 showed the compiler serializes plain loads
// (sinks subs into the load loop, ~2 in flight); R4's LDS staging killed
// occupancy (1 block/CU). Now: 20 asm-volatile global_load_dwordx4 per wave
// (compiler CANNOT reorder or early-wait), one manual vmcnt(0)+sched_barrier,
// then consume. Rows clamped so the load count is always exactly 20; OOB rows
// zeroed via mask multiply. 80 data VGPRs -> ~16 waves/CU -> 320KB in flight.

#define BB 16
#define HH 1024
#define WW 1024
#define RR 8   // rows per block-strip; load volume = (RR+2)/RR x ideal

typedef float f32x4 __attribute__((ext_vector_type(4)));

__device__ __forceinline__ float sl1(float v) {
  float ad = fabsf(v);
  float t = fminf(ad, 1.0f);
  return fmaf(0.5f * t, t, ad - t);   // ad<1 ? 0.5 ad^2 : ad-0.5
}

__global__ __launch_bounds__(256, 2) void smooth_partial(
    const float* __restrict__ in, const float* __restrict__ tg,
    float* __restrict__ ws) {
  const int tid  = threadIdx.x;
  const int lane = tid & 63;
  const int wave = tid >> 6;
  const int x0   = tid * 4;                 // 256 threads x 4 cols = W
  const int strip = blockIdx.x;             // 0 .. B*(H/RR)-1
  const int bi = strip >> 7;                // / (HH/RR) = /128
  const int r0 = (strip & 127) * RR;
  const float* baseIn = in + (size_t)bi * (HH * WW) + x0;
  const float* baseTg = tg + (size_t)bi * (HH * WW) + x0;

  // ---- phase 1: issue ALL 20 loads, immovable, no intervening waits ----
  f32x4 A[RR + 2], Bv[RR + 2];
  #pragma unroll
  for (int k = 0; k < RR + 2; ++k) {
    const int y  = r0 - 1 + k;
    const int yc = min(max(y, 0), HH - 1);       // clamp: always a real load
    const float* pa = baseIn + yc * WW;
    const float* pb = baseTg + yc * WW;
    asm volatile("global_load_dwordx4 %0, %1, off" : "=v"(A[k])  : "v"(pa));
    asm volatile("global_load_dwordx4 %0, %1, off" : "=v"(Bv[k]) : "v"(pb));
  }
  asm volatile("s_waitcnt vmcnt(0)" ::: "memory");
  __builtin_amdgcn_sched_barrier(0);  // rule 18: no consumer hoisted above wait

  // ---- phase 2: diffs (masked for OOB rows) + halos via shfl/LDS ----
  f32x4 Dc[RR + 2];
  float Dl[RR + 2], Dr[RR + 2];
  __shared__ float shL[4][RR + 2];   // lane63's Dc[3] per wave
  __shared__ float shR[4][RR + 2];   // lane0's  Dc[0] per wave

  #pragma unroll
  for (int k = 0; k < RR + 2; ++k) {
    const int y = r0 - 1 + k;
    const float m = (y >= 0 && y < HH) ? 1.f : 0.f;   // wave-uniform
    Dc[k][0] = (A[k][0] - Bv[k][0]) * m;
    Dc[k][1] = (A[k][1] - Bv[k][1]) * m;
    Dc[k][2] = (A[k][2] - Bv[k][2]) * m;
    Dc[k][3] = (A[k][3] - Bv[k][3]) * m;
    Dl[k] = __shfl_up(Dc[k][3], 1, 64);    // lane-1's col x0-1 (lane0 fixed below)
    Dr[k] = __shfl_down(Dc[k][0], 1, 64);  // lane+1's col x0+4 (lane63 fixed below)
    if (lane == 63) shL[wave][k] = Dc[k][3];
    if (lane == 0)  shR[wave][k] = Dc[k][0];
  }
  __syncthreads();
  #pragma unroll
  for (int k = 0; k < RR + 2; ++k) {
    if (lane == 0)  Dl[k] = (wave > 0) ? shL[wave - 1][k] : 0.f;  // x==0 pad
    if (lane == 63) Dr[k] = (wave < 3) ? shR[wave + 1][k] : 0.f;  // x==1023 pad
  }

  // ---- phase 3: stencils + smooth-L1 + masks ----
  float sum = 0.f;
  #pragma unroll
  for (int k = 0; k < RR; ++k) {
    const int y = r0 + k;
    const float my  = (y == HH - 1) ? 0.f : 1.f;
    const float mdy = (y == 0 || y == HH - 1) ? 0.f : 1.f;
    const float P[6] = {Dl[k  ], Dc[k  ][0], Dc[k  ][1], Dc[k  ][2], Dc[k  ][3], Dr[k  ]};
    const float C[6] = {Dl[k+1], Dc[k+1][0], Dc[k+1][1], Dc[k+1][2], Dc[k+1][3], Dr[k+1]};
    const float N[6] = {Dl[k+2], Dc[k+2][0], Dc[k+2][1], Dc[k+2][2], Dc[k+2][3], Dr[k+2]};
    #pragma unroll
    for (int j = 1; j <= 4; ++j) {
      const int x = x0 + j - 1;
      const float c2 = -2.f * C[j];
      const float fx = (C[j-1] + C[j+1]) + c2;
      const float fy = (P[j]   + N[j]  ) + c2;
      const float f1 = (P[j-1] + N[j+1]) + c2;
      const float f2 = (P[j+1] + N[j-1]) + c2;
      const float mx  = (x == WW - 1) ? 0.f : 1.f;
      const float mdx = (x == 0 || x == WW - 1) ? 0.f : 1.f;
      sum += sl1(fx) * mx + sl1(fy) * my + (sl1(f1) + sl1(f2)) * (mdx * mdy);
    }
  }

  // ---- deterministic block reduction ----
  for (int off = 32; off > 0; off >>= 1) sum += __shfl_down(sum, off, 64);
  __shared__ float shred[4];
  if (lane == 0) shred[wave] = sum;
  __syncthreads();
  if (tid == 0) ws[blockIdx.x] = (shred[0] + shred[1]) + (shred[2] + shred[3]);
}

__global__ __launch_bounds__(256) void smooth_final(
    const float* __restrict__ ws, float* __restrict__ out, int n) {
  float s = 0.f;
  for (int i = threadIdx.x; i < n; i += 256) s += ws[i];
  for (int off = 32; off > 0; off >>= 1) s += __shfl_down(s, off, 64);
  __shared__ float sh[4];
  const int wave = threadIdx.x >> 6, lane = threadIdx.x & 63;
  if (lane == 0) sh[wave] = s;
  __syncthreads();
  if (threadIdx.x == 0) {
    const float scale = 1.0f / (float)((long long)BB * 4LL * HH * WW);
    out[0] = ((sh[0] + sh[1]) + (sh[2] + sh[3])) * scale;
  }
}

extern "C" void kernel_launch(void* const* d_in, const int* in_sizes, int n_in,
                              void* d_out, int out_size, void* d_ws, size_t ws_size,
                              hipStream_t stream) {
  const float* in = (const float*)d_in[0];
  const float* tg = (const float*)d_in[1];
  float* out = (float*)d_out;
  float* ws  = (float*)d_ws;   // B*(H/RR)*4 = 8 KiB, well under ws_size

  const int nblocks = BB * (HH / RR);  // 2048 blocks, 256 threads each
  smooth_partial<<<nblocks, 256, 0, stream>>>(in, tg, ws);
  smooth_final<<<1, 256, 0, stream>>>(ws, out, nblocks);
}